// Round 9
// baseline (154.027 us; speedup 1.0000x reference)
//
#include <hip/hip_runtime.h>

#define NNODES 10000
#define NEDGES 160000
#define NB 8
#define NC 32
#define PADE 230016   // >= NEDGES + 7*NNODES (buckets padded to multiple of 8)
#define LUTB 2048
#define EBLKS 625     // (NEDGES+255)/256
#define FILLB 899     // (PADE+255)/256
#define G0BLKS 5000   // gather blocks: 2500 node-quads x 2 halves
constexpr float NEG_SLOPE = 0.01f;

__device__ __forceinline__ float sigmoidf_(float x) {
    return 1.0f / (1.0f + __expf(-x));
}

// pack two f32 -> one u32 holding bf16(a) in low16, bf16(b) in high16 (RNE)
__device__ __forceinline__ unsigned pk2bf(float a, float b) {
    unsigned ua = __float_as_uint(a);
    ua = (ua + 0x7fffu + ((ua >> 16) & 1u)) >> 16;
    unsigned ub = __float_as_uint(b);
    ub = (ub + 0x7fffu + ((ub >> 16) & 1u)) & 0xffff0000u;
    return ua | ub;
}

// ---- K1: fill sentinels + LUT + consts + dst histogram + node transform ----
// consts: [0:32) aq1, [32:64) ak1, [64:96) aq2, [96:128) ak2, [128] ce1, [129] ce2
// cnt must be zeroed before this kernel.
__global__ __launch_bounds__(256) void setup_hist_nt_kernel(
    const float* Q1, const float* K1, const float* aw1, const float* We1,
    const float* Q2, const float* K2, const float* aw2, const float* We2,
    const int* __restrict__ ei0, const int* __restrict__ ei1,
    float* consts, float* lut,
    int* pk1, int* pk2, float* wc1, float* wc2,
    int* __restrict__ cnt,
    unsigned* xs1h, unsigned* xs2h,
    float* sq1, float* sk1, float* sq2, float* sk2,
    const float* __restrict__ X, const float* __restrict__ Wn)
{
    int bx = blockIdx.x;
    int t = threadIdx.x;

    if (bx < 2 * EBLKS) {                       // histogram
        int layer = bx / EBLKS;
        int e = (bx % EBLKS) * 256 + t;
        const int* ei = layer ? ei1 : ei0;
        if (e < NEDGES) atomicAdd(&cnt[layer * NNODES + ei[NEDGES + e]], 1);
        return;
    }
    if (bx < 2 * EBLKS + FILLB) {               // fills
        int i = (bx - 2 * EBLKS) * 256 + t;
        if (i < PADE) {
            pk1[i] = NNODES; pk2[i] = NNODES;   // sentinel: src=NNODES (zero row), ix=0
            wc1[i] = 0.f;    wc2[i] = 0.f;
        }
        if (i < 2 * LUTB * 32) {                // sige LUT, both layers (f32 [2][2048][32])
            int layer = i >> 16;
            int bin   = (i >> 5) & (LUTB - 1);
            int o     = i & 31;
            float w   = (bin + 0.5f) * (1.0f / LUTB);
            float we  = layer ? We2[o] : We1[o];
            lut[i] = sigmoidf_(w * we);
        }
        if (i < 128) {                          // zero sentinel bf16 rows
            xs1h[(size_t)NNODES * 128 + i] = 0u;
            xs2h[(size_t)NNODES * 128 + i] = 0u;
        }
        if (i < NB) {
            sq1[NNODES * NB + i] = 0.f; sk1[NNODES * NB + i] = 0.f;
            sq2[NNODES * NB + i] = 0.f; sk2[NNODES * NB + i] = 0.f;
        }
        return;
    }
    if (bx == 2 * EBLKS + FILLB) {              // consts fold
        if (t < 32) {
            float aq1 = 0.f, ak1 = 0.f, aq2 = 0.f, ak2 = 0.f;
            for (int s = 0; s < 32; ++s) {
                aq1 += Q1[t * 32 + s] * aw1[s];
                ak1 += K1[t * 32 + s] * aw1[32 + s];
                aq2 += Q2[t * 32 + s] * aw2[s];
                ak2 += K2[t * 32 + s] * aw2[32 + s];
            }
            consts[t]      = aq1;
            consts[32 + t] = ak1;
            consts[64 + t] = aq2;
            consts[96 + t] = ak2;
            if (t == 0) {
                float ce1 = 0.f, ce2 = 0.f;
                for (int s = 0; s < 32; ++s) {
                    ce1 += We1[s] * aw1[64 + s];
                    ce2 += We2[s] * aw2[64 + s];
                }
                consts[128] = ce1;
                consts[129] = ce2;
            }
        }
        return;
    }

    // node transform: xs1h = bf16(X @ Wn) ; sq1 = xs.aq ; sk1 = xs.ak (X is [B,N,C])
    __shared__ float wnL[NC * NC];
    __shared__ float aqL[NC], akL[NC];
    __shared__ float xrow[4][NB][NC + 4];
    int w = t >> 6, l = t & 63, b = l >> 3, o4 = l & 7;
    int n = (bx - (2 * EBLKS + FILLB + 1)) * 4 + w;
    for (int i = t; i < NC * NC; i += 256) wnL[i] = Wn[i];
    if (t < 64) {                               // inline aq/ak fold
        int which = t >> 5, o = t & 31;
        const float* M  = which ? K1 : Q1;
        const float* av = aw1 + which * 32;
        float s = 0.f;
        for (int k = 0; k < 32; ++k) s += M[o * 32 + k] * av[k];
        (which ? akL : aqL)[o] = s;
    }
    const float4* X4 = (const float4*)X;
    float4 xv = X4[((size_t)b * NNODES + n) * 8 + o4];
    ((float4*)&xrow[w][b][0])[o4] = xv;
    __syncthreads();
    float4 aq = ((const float4*)aqL)[o4];
    float4 ak = ((const float4*)akL)[o4];
    const float4* wnL4 = (const float4*)wnL;
    float4 acc = {0.f, 0.f, 0.f, 0.f};
    #pragma unroll
    for (int c = 0; c < NC; ++c) {
        float xc = xrow[w][b][c];
        float4 w4 = wnL4[c * 8 + o4];
        acc.x += xc * w4.x; acc.y += xc * w4.y;
        acc.z += xc * w4.z; acc.w += xc * w4.w;
    }
    uint2 hp; hp.x = pk2bf(acc.x, acc.y); hp.y = pk2bf(acc.z, acc.w);
    ((uint2*)xs1h)[(size_t)n * 64 + l] = hp;
    float vq = acc.x * aq.x + acc.y * aq.y + acc.z * aq.z + acc.w * aq.w;
    float vk = acc.x * ak.x + acc.y * ak.y + acc.z * ak.z + acc.w * ak.w;
    #pragma unroll
    for (int m = 4; m >= 1; m >>= 1) {
        vq += __shfl_xor(vq, m);
        vk += __shfl_xor(vk, m);
    }
    if (o4 == 0) {
        sq1[n * NB + b] = vq;
        sk1[n * NB + b] = vk;
    }
}

// block per layer: exclusive scan of counts rounded up to multiple of 8
__global__ __launch_bounds__(1024) void scan_kernel(int* cnt01, int* rowptr01)
{
    __shared__ int part[1024];
    int layer = blockIdx.x;
    int* cnt    = cnt01 + layer * NNODES;
    int* rowptr = rowptr01 + layer * (NNODES + 1);
    int t = threadIdx.x;
    int base = t * 10;
    int local[10];
    int s = 0;
    #pragma unroll
    for (int i = 0; i < 10; ++i) {
        int idx = base + i;
        int v = (idx < NNODES) ? cnt[idx] : 0;
        int vp = (v + 7) & ~7;
        local[i] = s;
        s += vp;
    }
    part[t] = s;
    __syncthreads();
    for (int off = 1; off < 1024; off <<= 1) {
        int v = (t >= off) ? part[t - off] : 0;
        __syncthreads();
        part[t] += v;
        __syncthreads();
    }
    int pre = (t == 0) ? 0 : part[t - 1];
    #pragma unroll
    for (int i = 0; i < 10; ++i) {
        int idx = base + i;
        if (idx < NNODES) {
            int p = pre + local[i];
            rowptr[idx] = p;
            cnt[idx]    = p;            // becomes scatter cursor
        }
    }
    if (t == 1023) rowptr[NNODES] = part[1023];
}

// ---- K3: layer-1 edge scatter only (layer-2 scatter rides inside gather<0>) ----
__global__ __launch_bounds__(256) void scatter1_kernel(
    const int* __restrict__ ei0, const float* __restrict__ ew0,
    const float* __restrict__ ab1,
    int* __restrict__ cur1,
    int* __restrict__ pk1, float* __restrict__ wc1,
    const float* __restrict__ consts)
{
    int e = blockIdx.x * 256 + threadIdx.x;
    if (e < NEDGES) {
        float ce = consts[128];
        float ab = ab1[0];
        int dst = ei0[NEDGES + e];
        float w = ew0[e];
        int pos = atomicAdd(&cur1[dst], 1);
        int ix = (int)(w * (float)LUTB);
        ix = min(max(ix, 0), LUTB - 1);
        pk1[pos] = ei0[e] | (ix << 14);
        wc1[pos] = w * ce + ab;
    }
}

// Half-batch gather: wave = (node, half of 4 batches); lane = (b4 = l>>4, o16 = l&15).
// half = (bx>>2)&1 so bid%8 in {0..3} -> half 0, {4..7} -> half 1: each XCD's L2 sees
// only its half's 2.56 MB xs slice (L2-resident). One bf16x2 dword per lane per edge.
// MODE 0: fuse layer-2 node transform; blocks bx>=G0BLKS do the layer-2 scatter.
// MODE 1: final output [B,N,C].
template <int MODE>
__global__ __launch_bounds__(256) void gather_kernel(
    const int* __restrict__ rowptr, const int* __restrict__ pks, const float* __restrict__ wcs,
    const unsigned* __restrict__ xsh,
    const float* __restrict__ sq, const float* __restrict__ sk,
    const float* __restrict__ lut,
    const float* __restrict__ consts,
    const float* __restrict__ ow, const float* __restrict__ ob,
    const float* __restrict__ Wn2,
    unsigned* __restrict__ xs2h, float* __restrict__ sq2, float* __restrict__ sk2,
    float* __restrict__ outp,
    const int* __restrict__ ei1, const float* __restrict__ ew1,
    const float* __restrict__ ab2, int* __restrict__ cur2,
    int* __restrict__ pk2, float* __restrict__ wc2)
{
    int bx = blockIdx.x;
    int t = threadIdx.x;

    if (MODE == 0 && bx >= G0BLKS) {            // layer-2 scatter (runs concurrent)
        int e = (bx - G0BLKS) * 256 + t;
        if (e < NEDGES) {
            float ce = consts[129];
            float ab = ab2[0];
            int dst = ei1[NEDGES + e];
            float w = ew1[e];
            int pos = atomicAdd(&cur2[dst], 1);
            int ix = (int)(w * (float)LUTB);
            ix = min(max(ix, 0), LUTB - 1);
            pk2[pos] = ei1[e] | (ix << 14);
            wc2[pos] = w * ce + ab;
        }
        return;
    }

    __shared__ __align__(16) float owL[2 * NC * NC];                 // 8 KB
    __shared__ __align__(16) float wnL[(MODE == 0) ? NC * NC : 4];   // 4 KB (MODE 0)

    int w = t >> 6, l = t & 63, b4 = l >> 4, o16 = l & 15;
    int half = (bx >> 2) & 1;
    int q = ((bx >> 3) << 2) | (bx & 3);        // node-quad index in [0, 2500)
    int n = q * 4 + w;
    int b = half * 4 + b4;

    for (int i = t; i < 2 * NC * NC; i += 256) owL[i] = ow[i];
    if (MODE == 0)
        for (int i = t; i < NC * NC; i += 256) wnL[i] = Wn2[i];
    __syncthreads();   // only barrier

    const float2* owL2 = (const float2*)owL;
    const float2* wnL2 = (const float2*)wnL;
    const float2* LUT2 = (const float2*)lut;

    int row0 = rowptr[n];
    int degp = rowptr[n + 1] - row0;            // multiple of 8
    int ba = (l >> 3) & 3;                      // att-role batch (lanes 0..31 used)
    float skb = sk[n * NB + half * 4 + ba];
    unsigned hvs = xsh[(size_t)n * 128 + half * 64 + l];
    float2 xv;
    xv.x = __uint_as_float(hvs << 16);
    xv.y = __uint_as_float(hvs & 0xffff0000u);
    const int*   pkp = pks + row0;
    const float* wcp = wcs + row0;

    float2 acc = {0.f, 0.f};
    int pkv = NNODES; float wcv = 0.f, sqv = 0.f;
    if (degp > 0) {
        pkv = pkp[l & 7];                       // lane's att-role edge = l&7
        wcv = wcp[l & 7];
        sqv = sq[(pkv & 16383) * NB + half * 4 + ba];
    }
    for (int c0 = 0; c0 < degp; c0 += 8) {
        int pkv_n = NNODES; float wcv_n = 0.f, sqv_n = 0.f;
        int c1 = c0 + 8;
        if (c1 < degp) {                        // prefetch next chunk metadata + sq
            pkv_n = pkp[c1 + (l & 7)];
            wcv_n = wcp[c1 + (l & 7)];
            sqv_n = sq[(pkv_n & 16383) * NB + half * 4 + ba];
        }
        float att_own = sigmoidf_(sqv + skb + wcv);   // (edge l&7, batch ba)
        #pragma unroll
        for (int j = 0; j < 8; ++j) {
            int spk  = __builtin_amdgcn_readlane(pkv, j);   // SGPR: edge j metadata
            int ssrc = spk & 16383;
            int six  = (spk >> 14) & 2047;
            unsigned hv = xsh[(size_t)ssrc * 128 + half * 64 + l];  // scalar base + l
            float2 sg = LUT2[six * 16 + o16];
            float at = __shfl(att_own, ((l >> 4) << 3) + j);        // lane b4*8+j
            acc.x += at * sg.x * __uint_as_float(hv << 16);
            acc.y += at * sg.y * __uint_as_float(hv & 0xffff0000u);
        }
        pkv = pkv_n; wcv = wcv_n; sqv = sqv_n;
    }

    // wave-local epilogue: u = [xd, aggr] @ ow + ob for this (n, half)
    float2 uu = ((const float2*)ob)[o16];
    #pragma unroll
    for (int c16 = 0; c16 < 16; ++c16) {
        int sl = (l & 48) + c16;                // lane b4*16 + c16
        float xc0 = __shfl(xv.x, sl), xc1 = __shfl(xv.y, sl);
        float ac0 = __shfl(acc.x, sl), ac1 = __shfl(acc.y, sl);
        float2 w00 = owL2[(2 * c16) * 16 + o16];
        float2 w01 = owL2[(2 * c16 + 1) * 16 + o16];
        float2 w20 = owL2[(32 + 2 * c16) * 16 + o16];
        float2 w21 = owL2[(32 + 2 * c16 + 1) * 16 + o16];
        uu.x += xc0 * w00.x + xc1 * w01.x + ac0 * w20.x + ac1 * w21.x;
        uu.y += xc0 * w00.y + xc1 * w01.y + ac0 * w20.y + ac1 * w21.y;
    }
    float2 r2;
    r2.x = xv.x + uu.x; r2.y = xv.y + uu.y;
    r2.x = (r2.x > 0.f) ? r2.x : NEG_SLOPE * r2.x;
    r2.y = (r2.y > 0.f) ? r2.y : NEG_SLOPE * r2.y;

    if (MODE == 1) {
        ((float2*)outp)[((size_t)b * NNODES + n) * 16 + o16] = r2;
    } else {
        // fused layer-2 node transform for this half: xs2h = bf16(h @ Wn2); sq2, sk2
        float2 a2 = {0.f, 0.f};
        #pragma unroll
        for (int c16 = 0; c16 < 16; ++c16) {
            int sl = (l & 48) + c16;
            float h0 = __shfl(r2.x, sl), h1 = __shfl(r2.y, sl);
            float2 wn0 = wnL2[(2 * c16) * 16 + o16];
            float2 wn1 = wnL2[(2 * c16 + 1) * 16 + o16];
            a2.x += h0 * wn0.x + h1 * wn1.x;
            a2.y += h0 * wn0.y + h1 * wn1.y;
        }
        xs2h[(size_t)n * 128 + half * 64 + l] = pk2bf(a2.x, a2.y);
        float2 aqv = ((const float2*)(consts + 64))[o16];
        float2 akv = ((const float2*)(consts + 96))[o16];
        float vq = a2.x * aqv.x + a2.y * aqv.y;
        float vk = a2.x * akv.x + a2.y * akv.y;
        #pragma unroll
        for (int m = 8; m >= 1; m >>= 1) {      // reduce across the 16-lane o-group
            vq += __shfl_xor(vq, m);
            vk += __shfl_xor(vk, m);
        }
        if (o16 == 0) {
            sq2[n * NB + b] = vq;
            sk2[n * NB + b] = vk;
        }
    }
}

extern "C" void kernel_launch(void* const* d_in, const int* in_sizes, int n_in,
                              void* d_out, int out_size, void* d_ws, size_t ws_size,
                              hipStream_t stream) {
    const float* X    = (const float*)d_in[0];
    const int*   ei0  = (const int*)  d_in[1];
    const int*   ei1  = (const int*)  d_in[2];
    const float* ew0  = (const float*)d_in[3];
    const float* ew1  = (const float*)d_in[4];
    const float* Wn1  = (const float*)d_in[7];
    const float* We1  = (const float*)d_in[8];
    const float* Q1   = (const float*)d_in[9];
    const float* K1   = (const float*)d_in[10];
    const float* aw1  = (const float*)d_in[11];
    const float* ab1  = (const float*)d_in[12];
    const float* ow1  = (const float*)d_in[13];
    const float* ob1  = (const float*)d_in[14];
    const float* Wn2  = (const float*)d_in[15];
    const float* We2  = (const float*)d_in[16];
    const float* Q2   = (const float*)d_in[17];
    const float* K2   = (const float*)d_in[18];
    const float* aw2  = (const float*)d_in[19];
    const float* ab2  = (const float*)d_in[20];
    const float* ow2  = (const float*)d_in[21];
    const float* ob2  = (const float*)d_in[22];

    const size_t ROWH = (size_t)(NNODES + 1) * 128;      // u32 words per bf16 xs buffer
    const size_t SS   = (size_t)(NNODES + 1) * NB;
    unsigned* XS1H  = (unsigned*)d_ws;
    unsigned* XS2H  = XS1H + ROWH;
    float* SQ1    = (float*)(XS2H + ROWH);
    float* SK1    = SQ1 + SS;
    float* SQ2    = SK1 + SS;
    float* SK2    = SQ2 + SS;
    float* CONSTS = SK2 + SS;                            // 160
    float* LUT    = CONSTS + 160;                        // 2*LUTB*32 f32
    int* ROWPTR1  = (int*)(LUT + 2 * LUTB * 32);
    int* ROWPTR2  = ROWPTR1 + (NNODES + 1);
    int* CNT      = ROWPTR2 + (NNODES + 1);              // 2*N (hist -> cursor)
    int* PK1      = CNT + 2 * NNODES;
    int* PK2      = PK1 + PADE;
    float* WC1    = (float*)(PK2 + PADE);
    float* WC2    = WC1 + PADE;

    hipMemsetAsync(CNT, 0, 2 * NNODES * sizeof(int), stream);
    setup_hist_nt_kernel<<<2 * EBLKS + FILLB + 1 + NNODES / 4, 256, 0, stream>>>(
        Q1, K1, aw1, We1, Q2, K2, aw2, We2, ei0, ei1,
        CONSTS, LUT, PK1, PK2, WC1, WC2, CNT,
        XS1H, XS2H, SQ1, SK1, SQ2, SK2, X, Wn1);
    scan_kernel<<<2, 1024, 0, stream>>>(CNT, ROWPTR1);
    scatter1_kernel<<<EBLKS, 256, 0, stream>>>(
        ei0, ew0, ab1, CNT, PK1, WC1, CONSTS);

    gather_kernel<0><<<G0BLKS + EBLKS, 256, 0, stream>>>(
        ROWPTR1, PK1, WC1, XS1H, SQ1, SK1, LUT, CONSTS,
        ow1, ob1, Wn2, XS2H, SQ2, SK2, nullptr,
        ei1, ew1, ab2, CNT + NNODES, PK2, WC2);
    gather_kernel<1><<<G0BLKS, 256, 0, stream>>>(
        ROWPTR2, PK2, WC2, XS2H, SQ2, SK2, LUT + LUTB * 32, CONSTS,
        ow2, ob2, nullptr, nullptr, nullptr, nullptr, (float*)d_out,
        nullptr, nullptr, nullptr, nullptr, nullptr, nullptr);
}